// Round 3
// baseline (219.084 us; speedup 1.0000x reference)
//
#include <hip/hip_runtime.h>
#include <hip/hip_bf16.h>

// Problem constants (from reference)
#define BATCH_N   16384
#define FEAT      128      // MOVIE_FEAT == USER_FEAT
#define NNBR      50
#define NUM_MOVIES_N 100000

typedef short  short8  __attribute__((ext_vector_type(8)));
typedef float  floatx4 __attribute__((ext_vector_type(4)));

__device__ __forceinline__ __hip_bfloat16 f2bf(float x) { return __float2bfloat16(x); }

// XOR-swizzled LDS index for a [64][256] bf16 tile (no padding -> 32 KB).
// 16-B chunk c = col>>3 is XORed with (row&7) so that the 16 lrow-rows of an
// MFMA fragment read hit distinct 4-bank groups (2-way aliasing = free).
__device__ __forceinline__ int sw_idx(int r, int c) {
  return (r << 8) + ((((c >> 3) ^ (r & 7)) << 3) | (c & 7));
}

// ---------------------------------------------------------------------------
// conv_table: fp32 movie_table -> bf16 copy (25 MB, L2/L3-resident for gathers)
// ---------------------------------------------------------------------------
__global__ __launch_bounds__(256) void conv_table(
    const float* __restrict__ t, __hip_bfloat16* __restrict__ tb) {
  size_t i = ((size_t)blockIdx.x * 256 + threadIdx.x) * 8;
  float4 v0 = *(const float4*)(t + i);
  float4 v1 = *(const float4*)(t + i + 4);
  __hip_bfloat16 o[8];
  o[0] = f2bf(v0.x); o[1] = f2bf(v0.y); o[2] = f2bf(v0.z); o[3] = f2bf(v0.w);
  o[4] = f2bf(v1.x); o[5] = f2bf(v1.y); o[6] = f2bf(v1.z); o[7] = f2bf(v1.w);
  *(short8*)(tb + i) = *(short8*)o;
}

// ---------------------------------------------------------------------------
// prep: build bf16 transposed weights  Wt[n][k] + fused bias bu+bm.
// WcatT=[Wu;Wm]^T [256n][256k]; W1T [256][256]; W2T [128n][256k]; WmT [256n][128k]
// ---------------------------------------------------------------------------
__global__ __launch_bounds__(256) void prep_kernel(
    const float* __restrict__ Wu, const float* __restrict__ Wm,
    const float* __restrict__ W1, const float* __restrict__ W2,
    const float* __restrict__ bu, const float* __restrict__ bm,
    __hip_bfloat16* __restrict__ WcatT, __hip_bfloat16* __restrict__ WmT,
    __hip_bfloat16* __restrict__ W1T,  __hip_bfloat16* __restrict__ W2T,
    float* __restrict__ bc) {
  int idx = blockIdx.x * 256 + threadIdx.x;   // 0..65535
  int n = idx & 255, k = idx >> 8;            // reads coalesced over n
  float v = (k < 128) ? Wu[k * 256 + n] : Wm[(k - 128) * 256 + n];
  WcatT[n * 256 + k] = f2bf(v);
  W1T[n * 256 + k]   = f2bf(W1[k * 256 + n]);
  if (k < 128) WmT[n * 128 + k] = f2bf(Wm[k * 256 + n]);
  if (idx < 32768) {
    int k2 = idx >> 7, n2 = idx & 127;
    W2T[n2 * 256 + k2] = f2bf(W2[k2 * 128 + n2]);
  }
  if (idx < 256) bc[idx] = bu[idx] + bm[idx];
}

// ---------------------------------------------------------------------------
// gather_user: one wave per batch row, bf16 table (256 B/row).
// A_user[b] = [ users[b] (fp32->bf16) | (1/50)*sum_j tb[nbr_ids[b][j]] ]
// ---------------------------------------------------------------------------
__global__ __launch_bounds__(256) void gather_user(
    const float* __restrict__ users, const int* __restrict__ nbr_ids,
    const __hip_bfloat16* __restrict__ tb, __hip_bfloat16* __restrict__ A_user) {
  int row  = (blockIdx.x << 2) + (threadIdx.x >> 6);
  int lane = threadIdx.x & 63;
  const int* nb = nbr_ids + row * NNBR;
  float ax = 0.f, ay = 0.f;
  #pragma unroll 5
  for (int j = 0; j < NNBR; ++j) {
    int id = nb[j];
    __hip_bfloat162 v = ((const __hip_bfloat162*)(tb + (size_t)id * FEAT))[lane];
    ax += __bfloat162float(v.x); ay += __bfloat162float(v.y);
  }
  ax *= (1.f / NNBR); ay *= (1.f / NNBR);
  float2 uv = ((const float2*)(users + (size_t)row * FEAT))[lane];
  __hip_bfloat162* dst = (__hip_bfloat162*)(A_user + (size_t)row * (2 * FEAT));
  __hip_bfloat162 t0; t0.x = f2bf(uv.x); t0.y = f2bf(uv.y);
  __hip_bfloat162 t1; t1.x = f2bf(ax);   t1.y = f2bf(ay);
  dst[lane]      = t0;
  dst[64 + lane] = t1;
}

// ---------------------------------------------------------------------------
// fused_mlp: one block = 64 batch rows of one stream (y: 0=user,1=pos,2=neg).
// Stage A tile into LDS (pos/neg gather tb rows by id directly), then
//   E = A @ W0^T + bias0          (K0 = 256 user / 128 pn)   -> E_lds
//   H = relu(E @ W1^T + b1)                                   -> A_lds
//   O = relu(H @ W2^T + b2)       (N = 128)                   -> out
// B-fragments are loaded straight from the L2-resident weight tables (~300 KB
// shared by all 768 blocks) — no B staging, one barrier per layer.
// 4 waves in 2(m)x2(n); per wave 32x128 output (2x8 MFMA tiles of 16x16x32).
// MFMA layouts (R1-verified): A frag lane l elem j = A[l&15][(l>>4)*8+j];
// B frag = Wt[l&15][(l>>4)*8+j]; C/D lane l reg r -> row=(l>>4)*4+r, col=l&15.
// ---------------------------------------------------------------------------
__global__ __launch_bounds__(256, 2) void fused_mlp(
    const __hip_bfloat16* __restrict__ A_user,
    const __hip_bfloat16* __restrict__ tb,
    const int* __restrict__ pos_ids, const int* __restrict__ neg_ids,
    const __hip_bfloat16* __restrict__ WcatT,
    const __hip_bfloat16* __restrict__ WmT,
    const __hip_bfloat16* __restrict__ W1T,
    const __hip_bfloat16* __restrict__ W2T,
    const float* __restrict__ bc, const float* __restrict__ bmv,
    const float* __restrict__ b1, const float* __restrict__ b2,
    float* __restrict__ out) {
  __shared__ __hip_bfloat16 A_lds[64 * 256];   // 32 KB
  __shared__ __hip_bfloat16 E_lds[64 * 256];   // 32 KB

  const int t    = threadIdx.x;
  const int lane = t & 63, wid = t >> 6;
  const int wm   = wid & 1, wn = wid >> 1;
  const int quad = lane >> 4, lrow = lane & 15;
  const int s    = blockIdx.y;
  const int m0   = blockIdx.x * 64;

  // ---- stage A tile ----
  if (s == 0) {
    #pragma unroll
    for (int c = 0; c < 8; ++c) {
      int ch = t + c * 256;                 // 2048 chunks of 16 B
      int r = ch >> 5, kc = (ch & 31) << 3;
      *(short8*)&A_lds[sw_idx(r, kc)] =
          *(const short8*)(A_user + ((size_t)(m0 + r) << 8) + kc);
    }
  } else {
    const int* ids = (s == 1) ? pos_ids : neg_ids;
    #pragma unroll
    for (int c = 0; c < 4; ++c) {
      int ch = t + c * 256;                 // 1024 chunks of 16 B
      int r = ch >> 4, kc = (ch & 15) << 3;
      int id = ids[m0 + r];
      *(short8*)&A_lds[sw_idx(r, kc)] =
          *(const short8*)(tb + ((size_t)id << 7) + kc);
    }
  }
  __syncthreads();

  const __hip_bfloat16* W0 = (s == 0) ? WcatT : WmT;
  const float* bias0 = (s == 0) ? bc : bmv;
  const int K0 = (s == 0) ? 256 : 128;

  // ---- layer 0: E_lds = A @ W0^T + bias0 (no relu) ----
  {
    floatx4 acc[2][8] = {};
    for (int k0 = 0; k0 < K0; k0 += 32) {
      short8 af[2];
      #pragma unroll
      for (int i = 0; i < 2; ++i)
        af[i] = *(const short8*)&A_lds[sw_idx(wm * 32 + i * 16 + lrow, k0 + quad * 8)];
      #pragma unroll
      for (int j = 0; j < 8; ++j) {
        int n = wn * 128 + j * 16 + lrow;
        short8 bf = *(const short8*)(W0 + (size_t)n * K0 + k0 + quad * 8);
        #pragma unroll
        for (int i = 0; i < 2; ++i)
          acc[i][j] = __builtin_amdgcn_mfma_f32_16x16x32_bf16(af[i], bf, acc[i][j], 0, 0, 0);
      }
    }
    #pragma unroll
    for (int j = 0; j < 8; ++j) {
      int col = wn * 128 + j * 16 + lrow;
      float bv = bias0[col];
      #pragma unroll
      for (int i = 0; i < 2; ++i)
        #pragma unroll
        for (int r = 0; r < 4; ++r) {
          int row = wm * 32 + i * 16 + quad * 4 + r;
          E_lds[sw_idx(row, col)] = f2bf(acc[i][j][r] + bv);
        }
    }
  }
  __syncthreads();

  // ---- layer 1: A_lds = relu(E @ W1^T + b1) ----
  {
    floatx4 acc[2][8] = {};
    for (int k0 = 0; k0 < 256; k0 += 32) {
      short8 af[2];
      #pragma unroll
      for (int i = 0; i < 2; ++i)
        af[i] = *(const short8*)&E_lds[sw_idx(wm * 32 + i * 16 + lrow, k0 + quad * 8)];
      #pragma unroll
      for (int j = 0; j < 8; ++j) {
        int n = wn * 128 + j * 16 + lrow;
        short8 bf = *(const short8*)(W1T + ((size_t)n << 8) + k0 + quad * 8);
        #pragma unroll
        for (int i = 0; i < 2; ++i)
          acc[i][j] = __builtin_amdgcn_mfma_f32_16x16x32_bf16(af[i], bf, acc[i][j], 0, 0, 0);
      }
    }
    #pragma unroll
    for (int j = 0; j < 8; ++j) {
      int col = wn * 128 + j * 16 + lrow;
      float bv = b1[col];
      #pragma unroll
      for (int i = 0; i < 2; ++i)
        #pragma unroll
        for (int r = 0; r < 4; ++r) {
          int row = wm * 32 + i * 16 + quad * 4 + r;
          A_lds[sw_idx(row, col)] = f2bf(fmaxf(acc[i][j][r] + bv, 0.f));
        }
    }
  }
  __syncthreads();

  // ---- layer 2: out = relu(H @ W2^T + b2), N = 128 ----
  {
    floatx4 acc[2][4] = {};
    for (int k0 = 0; k0 < 256; k0 += 32) {
      short8 af[2];
      #pragma unroll
      for (int i = 0; i < 2; ++i)
        af[i] = *(const short8*)&A_lds[sw_idx(wm * 32 + i * 16 + lrow, k0 + quad * 8)];
      #pragma unroll
      for (int j = 0; j < 4; ++j) {
        int n = wn * 64 + j * 16 + lrow;
        short8 bf = *(const short8*)(W2T + ((size_t)n << 8) + k0 + quad * 8);
        #pragma unroll
        for (int i = 0; i < 2; ++i)
          acc[i][j] = __builtin_amdgcn_mfma_f32_16x16x32_bf16(af[i], bf, acc[i][j], 0, 0, 0);
      }
    }
    #pragma unroll
    for (int j = 0; j < 4; ++j) {
      int col = wn * 64 + j * 16 + lrow;
      float bv = b2[col];
      #pragma unroll
      for (int i = 0; i < 2; ++i)
        #pragma unroll
        for (int r = 0; r < 4; ++r) {
          int row = wm * 32 + i * 16 + quad * 4 + r;
          float v = fmaxf(acc[i][j][r] + bv, 0.f);
          out[((size_t)s * BATCH_N + m0 + row) * 128 + col] = v;
        }
    }
  }
}

// ---------------------------------------------------------------------------
extern "C" void kernel_launch(void* const* d_in, const int* in_sizes, int n_in,
                              void* d_out, int out_size, void* d_ws, size_t ws_size,
                              hipStream_t stream) {
  const float* users   = (const float*)d_in[0];
  // d_in[1] pos_movies, d_in[2] neg_movies, d_in[3] user_ids: unused by ref
  const int*   pos_ids = (const int*)d_in[4];
  const int*   neg_ids = (const int*)d_in[5];
  const int*   nbr_ids = (const int*)d_in[6];
  const float* table   = (const float*)d_in[7];
  const float* Wu = (const float*)d_in[8];
  const float* bu = (const float*)d_in[9];
  const float* Wm = (const float*)d_in[10];
  const float* bm = (const float*)d_in[11];
  const float* W1 = (const float*)d_in[12];
  const float* b1 = (const float*)d_in[13];
  const float* W2 = (const float*)d_in[14];
  const float* b2 = (const float*)d_in[15];
  float* out = (float*)d_out;

  // workspace carve (all 256B aligned). Total ~34 MB.
  char* p = (char*)d_ws;
  auto carve = [&](size_t bytes) { char* r = p; p += (bytes + 255) & ~(size_t)255; return r; };
  __hip_bfloat16* tb     = (__hip_bfloat16*)carve((size_t)NUM_MOVIES_N * FEAT * 2);
  __hip_bfloat16* WcatT  = (__hip_bfloat16*)carve(256 * 256 * 2);
  __hip_bfloat16* WmT    = (__hip_bfloat16*)carve(256 * 128 * 2);
  __hip_bfloat16* W1T    = (__hip_bfloat16*)carve(256 * 256 * 2);
  __hip_bfloat16* W2T    = (__hip_bfloat16*)carve(128 * 256 * 2);
  float*          bc     = (float*)carve(256 * 4);
  __hip_bfloat16* A_user = (__hip_bfloat16*)carve((size_t)BATCH_N * 256 * 2);

  conv_table<<<NUM_MOVIES_N * FEAT / (256 * 8), 256, 0, stream>>>(table, tb);
  prep_kernel<<<256, 256, 0, stream>>>(Wu, Wm, W1, W2, bu, bm,
                                       WcatT, WmT, W1T, W2T, bc);
  gather_user<<<BATCH_N / 4, 256, 0, stream>>>(users, nbr_ids, tb, A_user);
  fused_mlp<<<dim3(BATCH_N / 64, 3), 256, 0, stream>>>(
      A_user, tb, pos_ids, neg_ids, WcatT, WmT, W1T, W2T,
      bc, bm, b1, b2, out);
}

// Round 4
// 214.878 us; speedup vs baseline: 1.0196x; 1.0196x over previous
//
#include <hip/hip_runtime.h>
#include <hip/hip_bf16.h>

// Problem constants (from reference)
#define BATCH_N   16384
#define FEAT      128      // MOVIE_FEAT == USER_FEAT
#define NNBR      50
#define NUM_MOVIES_N 100000

typedef short  short8  __attribute__((ext_vector_type(8)));
typedef float  floatx4 __attribute__((ext_vector_type(4)));
typedef unsigned int u32;

__device__ __forceinline__ __hip_bfloat16 f2bf(float x) { return __float2bfloat16(x); }
__device__ __forceinline__ float bfb2f(short s) {
  union { u32 u; float f; } c; c.u = ((u32)(unsigned short)s) << 16; return c.f;
}

// async global->LDS 16B DMA. HW rule (m104): LDS dst = wave-uniform base +
// lane*16 — all callers keep dst linear in lane and swizzle the SOURCE index.
__device__ __forceinline__ void gld16(const __hip_bfloat16* g, __hip_bfloat16* l) {
  __builtin_amdgcn_global_load_lds(
      (const __attribute__((address_space(1))) u32*)g,
      (__attribute__((address_space(3))) u32*)l, 16, 0, 0);
}

__device__ __forceinline__ floatx4 mfma16(short8 a, short8 b, floatx4 c) {
  return __builtin_amdgcn_mfma_f32_16x16x32_bf16(a, b, c, 0, 0, 0);
}

// ---------------------------------------------------------------------------
// conv_table: fp32 movie_table -> bf16 copy (25 MB, L2/L3-resident for gathers)
// ---------------------------------------------------------------------------
__global__ __launch_bounds__(256) void conv_table(
    const float* __restrict__ t, __hip_bfloat16* __restrict__ tb) {
  size_t i = ((size_t)blockIdx.x * 256 + threadIdx.x) * 8;
  float4 v0 = *(const float4*)(t + i);
  float4 v1 = *(const float4*)(t + i + 4);
  __hip_bfloat16 o[8];
  o[0] = f2bf(v0.x); o[1] = f2bf(v0.y); o[2] = f2bf(v0.z); o[3] = f2bf(v0.w);
  o[4] = f2bf(v1.x); o[5] = f2bf(v1.y); o[6] = f2bf(v1.z); o[7] = f2bf(v1.w);
  *(short8*)(tb + i) = *(short8*)o;
}

// ---------------------------------------------------------------------------
// prep: bf16 transposed weights Wt[n][k] + fused bias bu+bm.
// WcatT=[Wu;Wm]^T [256n][256k]; W1T [256][256]; W2T [128n][256k]; WmT [256n][128k]
// ---------------------------------------------------------------------------
__global__ __launch_bounds__(256) void prep_kernel(
    const float* __restrict__ Wu, const float* __restrict__ Wm,
    const float* __restrict__ W1, const float* __restrict__ W2,
    const float* __restrict__ bu, const float* __restrict__ bm,
    __hip_bfloat16* __restrict__ WcatT, __hip_bfloat16* __restrict__ WmT,
    __hip_bfloat16* __restrict__ W1T,  __hip_bfloat16* __restrict__ W2T,
    float* __restrict__ bc) {
  int idx = blockIdx.x * 256 + threadIdx.x;   // 0..65535
  int n = idx & 255, k = idx >> 8;
  float v = (k < 128) ? Wu[k * 256 + n] : Wm[(k - 128) * 256 + n];
  WcatT[n * 256 + k] = f2bf(v);
  W1T[n * 256 + k]   = f2bf(W1[k * 256 + n]);
  if (k < 128) WmT[n * 128 + k] = f2bf(Wm[k * 256 + n]);
  if (idx < 32768) {
    int k2 = idx >> 7, n2 = idx & 127;
    W2T[n2 * 256 + k2] = f2bf(W2[k2 * 128 + n2]);
  }
  if (idx < 256) bc[idx] = bu[idx] + bm[idx];
}

// ---------------------------------------------------------------------------
// gather_user v2: one WAVE per batch row. Lane slice = 16 B (8 bf16 elems);
// 4 neighbor rows per load instr (quad q handles nbr 4*it+q) -> 13 loads of
// 1 KB instead of 50 loads of 256 B. Cross-quad shfl_xor reduce at the end.
// ---------------------------------------------------------------------------
__global__ __launch_bounds__(256) void gather_user(
    const float* __restrict__ users, const int* __restrict__ nbr_ids,
    const __hip_bfloat16* __restrict__ tb, __hip_bfloat16* __restrict__ A_user) {
  int row  = (blockIdx.x << 2) + (threadIdx.x >> 6);
  int lane = threadIdx.x & 63;
  int quad = lane >> 4, sl = lane & 15;
  const int* nb = nbr_ids + row * NNBR;
  float acc[8] = {0.f, 0.f, 0.f, 0.f, 0.f, 0.f, 0.f, 0.f};
  #pragma unroll
  for (int it = 0; it < 13; ++it) {
    int j = it * 4 + quad;
    if (j < NNBR) {
      int id = nb[j];
      short8 v = *(const short8*)(tb + (size_t)id * FEAT + sl * 8);
      #pragma unroll
      for (int e = 0; e < 8; ++e) acc[e] += bfb2f(v[e]);
    }
  }
  __hip_bfloat16 o[8];
  #pragma unroll
  for (int e = 0; e < 8; ++e) {
    float v = acc[e];
    v += __shfl_xor(v, 16, 64);
    v += __shfl_xor(v, 32, 64);
    o[e] = f2bf(v * (1.f / NNBR));
  }
  if (quad == 0)
    *(short8*)(A_user + (size_t)row * 256 + 128 + sl * 8) = *(short8*)o;
  float2 uv = ((const float2*)(users + (size_t)row * FEAT))[lane];
  __hip_bfloat162 t0; t0.x = f2bf(uv.x); t0.y = f2bf(uv.y);
  ((__hip_bfloat162*)(A_user + (size_t)row * 256))[lane] = t0;
}

// ---------------------------------------------------------------------------
// run_layer: one fused-MLP GEMM layer on a 64-row tile.
//   Ain: LDS, 64 rows x K0 elems, XOR-swizzled (chunk ^= row&7).
//   Bst: LDS staging for W chunks [NCOL n][32 k], chunk' = q ^ ((n>>1)&3).
//   W:   global [NCOL][K0] row-major bf16 (pre-transposed).
// K-loop: m97 2-barrier structure with global_load_lds width-16 staging.
// 4 waves 2(m)x2(n); wave = 32 rows x NCOL/2 cols via 2 x JN 16x16x32 MFMAs.
// Post-loop barrier lets the epilogue safely overwrite the (aliased) Bst/Ain
// regions. Output: LDS (256-col swizzled) or global fp32 (128-col).
// ---------------------------------------------------------------------------
template <int K0, int NCOL, bool RELU, bool TOGLB>
__device__ __forceinline__ void run_layer(
    const __hip_bfloat16* Ain, __hip_bfloat16* Bst,
    const __hip_bfloat16* __restrict__ W, const float* __restrict__ bias,
    __hip_bfloat16* Olds, float* __restrict__ Oglb,
    int t, int wm, int wn, int quad, int lrow, long m0) {
  constexpr int KK = K0 / 32;
  constexpr int JN = NCOL / 32;          // j-tiles per wave (8 or 4)
  floatx4 acc[2][JN] = {};
  for (int kc = 0; kc < KK; ++kc) {
    const int k0 = kc * 32;
    __syncthreads();                     // Bst region free (all readers done)
    #pragma unroll
    for (int i = 0; i < NCOL / 64; ++i) {
      int c = t + i * 256;               // linear 16-B chunk -> lane*16 rule OK
      int n = c >> 2, q = c & 3;
      gld16(W + (size_t)n * K0 + k0 + ((q ^ ((n >> 1) & 3)) << 3),
            Bst + (c << 3));
    }
    __syncthreads();                     // staged data visible (vmcnt drained)
    short8 af[2];
    #pragma unroll
    for (int i = 0; i < 2; ++i) {
      int r = wm * 32 + i * 16 + lrow;
      af[i] = *(const short8*)&Ain[r * K0 + ((((k0 >> 3) + quad) ^ (r & 7)) << 3)];
    }
    #pragma unroll
    for (int j = 0; j < JN; ++j) {
      int n = wn * (NCOL / 2) + j * 16 + lrow;
      short8 bf = *(const short8*)&Bst[n * 32 + ((quad ^ ((n >> 1) & 3)) << 3)];
      acc[0][j] = mfma16(af[0], bf, acc[0][j]);
      acc[1][j] = mfma16(af[1], bf, acc[1][j]);
    }
  }
  __syncthreads();                       // all LDS reads done -> may overwrite
  #pragma unroll
  for (int j = 0; j < JN; ++j) {
    int col = wn * (NCOL / 2) + j * 16 + lrow;
    float bv = bias[col];
    #pragma unroll
    for (int i = 0; i < 2; ++i)
      #pragma unroll
      for (int r = 0; r < 4; ++r) {
        int row = wm * 32 + i * 16 + quad * 4 + r;
        float v = acc[i][j][r] + bv;
        if (RELU) v = fmaxf(v, 0.f);
        if (TOGLB) {
          Oglb[(m0 + row) * 128 + col] = v;
        } else {
          int ch = col >> 3;
          Olds[row * 256 + (((ch ^ (row & 7)) << 3) | (col & 7))] = f2bf(v);
        }
      }
  }
}

// ---------------------------------------------------------------------------
// fused_mlp: one block = 64 rows of stream s (0 user / 1 pos / 2 neg).
// A staged via global_load_lds (pos/neg gather tb rows by id). 3 layers with
// B staged through LDS; E/H live only in LDS. B-staging buffers alias dead
// activation regions: L0/L2 -> E region, L1 -> A region (post-loop barrier
// makes that safe). LDS total 64 KB -> 2 blocks/CU.
// ---------------------------------------------------------------------------
__global__ __launch_bounds__(256, 2) void fused_mlp(
    const __hip_bfloat16* __restrict__ A_user,
    const __hip_bfloat16* __restrict__ tb,
    const int* __restrict__ pos_ids, const int* __restrict__ neg_ids,
    const __hip_bfloat16* __restrict__ WcatT,
    const __hip_bfloat16* __restrict__ WmT,
    const __hip_bfloat16* __restrict__ W1T,
    const __hip_bfloat16* __restrict__ W2T,
    const float* __restrict__ bc, const float* __restrict__ bmv,
    const float* __restrict__ b1, const float* __restrict__ b2,
    float* __restrict__ out) {
  __shared__ __hip_bfloat16 A_lds[64 * 256];   // 32 KB: A / Bst(L1) / H
  __shared__ __hip_bfloat16 E_lds[64 * 256];   // 32 KB: Bst(L0) / E / Bst(L2)

  const int t    = threadIdx.x;
  const int lane = t & 63, wid = t >> 6;
  const int wm   = wid & 1, wn = wid >> 1;
  const int quad = lane >> 4, lrow = lane & 15;
  const int bx   = blockIdx.x;
  const int s    = bx % 3;                     // interleave streams across CUs
  const long m0  = (long)(bx / 3) * 64;

  // ---- stage A tile (async; drained by first k-chunk's 2nd barrier) ----
  if (s == 0) {
    #pragma unroll
    for (int i = 0; i < 8; ++i) {
      int c = t + i * 256;                     // 2048 chunks: r=c>>5, kq=c&31
      int r = c >> 5, kq = c & 31;
      gld16(A_user + ((size_t)(m0 + r) << 8) + ((kq ^ (r & 7)) << 3),
            A_lds + (c << 3));
    }
  } else {
    const int* ids = (s == 1) ? pos_ids : neg_ids;
    #pragma unroll
    for (int i = 0; i < 4; ++i) {
      int c = t + i * 256;                     // 1024 chunks: r=c>>4, kq=c&15
      int r = c >> 4, kq = c & 15;
      int id = ids[m0 + r];
      gld16(tb + ((size_t)id << 7) + ((kq ^ (r & 7)) << 3),
            A_lds + (c << 3));
    }
  }

  // ---- layer 0 -> E (no relu) ----
  if (s == 0)
    run_layer<256, 256, false, false>(A_lds, E_lds, WcatT, bc, E_lds, nullptr,
                                      t, wm, wn, quad, lrow, m0);
  else
    run_layer<128, 256, false, false>(A_lds, E_lds, WmT, bmv, E_lds, nullptr,
                                      t, wm, wn, quad, lrow, m0);

  // ---- layer 1: H = relu(E @ W1^T + b1) -> A region ----
  run_layer<256, 256, true, false>(E_lds, A_lds, W1T, b1, A_lds, nullptr,
                                   t, wm, wn, quad, lrow, m0);

  // ---- layer 2: out = relu(H @ W2^T + b2), N=128 -> global ----
  run_layer<256, 128, true, true>(A_lds, E_lds, W2T, b2, nullptr,
                                  out + (size_t)s * BATCH_N * 128,
                                  t, wm, wn, quad, lrow, m0);
}

// ---------------------------------------------------------------------------
extern "C" void kernel_launch(void* const* d_in, const int* in_sizes, int n_in,
                              void* d_out, int out_size, void* d_ws, size_t ws_size,
                              hipStream_t stream) {
  const float* users   = (const float*)d_in[0];
  // d_in[1] pos_movies, d_in[2] neg_movies, d_in[3] user_ids: unused by ref
  const int*   pos_ids = (const int*)d_in[4];
  const int*   neg_ids = (const int*)d_in[5];
  const int*   nbr_ids = (const int*)d_in[6];
  const float* table   = (const float*)d_in[7];
  const float* Wu = (const float*)d_in[8];
  const float* bu = (const float*)d_in[9];
  const float* Wm = (const float*)d_in[10];
  const float* bm = (const float*)d_in[11];
  const float* W1 = (const float*)d_in[12];
  const float* b1 = (const float*)d_in[13];
  const float* W2 = (const float*)d_in[14];
  const float* b2 = (const float*)d_in[15];
  float* out = (float*)d_out;

  // workspace carve (all 256B aligned). Total ~34 MB.
  char* p = (char*)d_ws;
  auto carve = [&](size_t bytes) { char* r = p; p += (bytes + 255) & ~(size_t)255; return r; };
  __hip_bfloat16* tb     = (__hip_bfloat16*)carve((size_t)NUM_MOVIES_N * FEAT * 2);
  __hip_bfloat16* WcatT  = (__hip_bfloat16*)carve(256 * 256 * 2);
  __hip_bfloat16* WmT    = (__hip_bfloat16*)carve(256 * 128 * 2);
  __hip_bfloat16* W1T    = (__hip_bfloat16*)carve(256 * 256 * 2);
  __hip_bfloat16* W2T    = (__hip_bfloat16*)carve(128 * 256 * 2);
  float*          bc     = (float*)carve(256 * 4);
  __hip_bfloat16* A_user = (__hip_bfloat16*)carve((size_t)BATCH_N * 256 * 2);

  conv_table<<<NUM_MOVIES_N * FEAT / (256 * 8), 256, 0, stream>>>(table, tb);
  prep_kernel<<<256, 256, 0, stream>>>(Wu, Wm, W1, W2, bu, bm,
                                       WcatT, WmT, W1T, W2T, bc);
  gather_user<<<BATCH_N / 4, 256, 0, stream>>>(users, nbr_ids, tb, A_user);
  fused_mlp<<<dim3(3 * BATCH_N / 64), 256, 0, stream>>>(
      A_user, tb, pos_ids, neg_ids, WcatT, WmT, W1T, W2T,
      bc, bm, b1, b2, out);
}